// Round 5
// baseline (113.849 us; speedup 1.0000x reference)
//
#include <hip/hip_runtime.h>

// CRITICAL: hipcc defaults to -ffp-contract=fast-honor-pragmas, and HIP's
// __fmul_rn/__fadd_rn are PLAIN OPERATORS (not contraction barriers like
// CUDA). This pragma guarantees mul/add are not fused into v_fmac/v_pk_fma,
// so our rounding matches numpy's exactly. (R4 proved this: absmax == 0.0.)
#pragma clang fp contract(off)

// NOTE (R10): op_sel on pk_f32 is illegal (aborts). 
// NOTE (R12/R13 fit): v_pk_*_f32 on gfx950 measures as ~8 cyc/instr
// (HALF the per-component throughput of scalar v_mul/v_add_f32) — the
// 58-61 µs walls across 2.4/3.9 waves-per-SIMD occupancies fit pk=8cyc and
// reject pk=4cyc. R14 is the discriminating experiment: scalar math,
// identical rn rounding and association order.
static __device__ __forceinline__ float min3f(float a, float b, float c) {
    float d;
    asm("v_min3_f32 %0, %1, %2, %3" : "=v"(d) : "v"(a), "v"(b), "v"(c));
    return d;
}

// Problem constants (from reference): B=4, N=16384, M=4096, D=64
#define MM 4096
#define DD 64
#define BN 65536                  // B*N points
#define FEATS_OFF 0               // feats: BN*DD floats
#define IDS_OFF (BN * DD)         // ids:   BN floats (ints stored as float)
#define PC_OFF (IDS_OFF + BN)     // pc:    BN*3 floats passthrough

#define BLK 512                   // threads per block (8 waves)
#define CC 32                     // lanes per point
#define PP 4                      // points per thread (register tile)
#define PPB 64                    // points per block (BLK*PP/CC)
#define NPAIR (MM / 2)            // 2048 key pairs
#define KIT (MM / (2 * CC))       // 64 main-loop iterations

// NUMERICS (bit-exact vs numpy fp32 replay — verified R4-R8):
//  - keys stored NEGATED+DOUBLED: rn commutes with sign and 2^k scaling, so
//    cross' = ((px*(-2kx) + py*(-2ky)) + pz*(-2kz)) == -2*cross bit-exact,
//    and d2 = (psq + cross') + ksq == (psq - 2*cross) + ksq == ref bits.
//  - all plain rn (contract off); k_sq/p_sq ascending plain. FMA / dropping
//    psq / MFMA are all FORBIDDEN: each changes rounding, and a
//    rounding-created tie flips argmin's first-index rule.
//  - per-key evaluation here is the SAME scalar expression as the verified
//    recovery epilogue: cross' = ((px*kx)+(py*ky))+(pz*kz);
//    d = (psq+cross')+ksq — association order identical to the pk
//    per-component sequence used R9-R13 (bit-identical).
//  - argmin: bd via v_min3 (== sequential strict-'<' min, no NaNs); bk =
//    first iter where bd strictly dropped (later equal values don't
//    overwrite => first-index kept); within-pair even preferred on tie at
//    recovery; lexicographic (d2,id) butterfly across lanes.
//
// STRUCTURE (R14): R13 falsified latency-hiding (occupancy +60%, dur flat)
// => a saturated shared pipe. Cycle-model fit across R9/R12/R13 says
// v_pk_*_f32 = 8 cyc (half-rate packed fp32). This round: identical
// structure to R12 (BLK=512, PP=4, 64KiB key table, waves_per_eu(4,4) —
// best measured, no spills), with the pk inner math replaced by 14 scalar
// rn ops per key-pair per point (compiler-scheduled). If pk was half-rate,
// ~58 -> ~35 µs; if issue-slots were binding, this regresses and the
// next target is the LDS path.
__global__ __launch_bounds__(BLK) __attribute__((amdgpu_waves_per_eu(4, 4)))
void quant_embed_kernel(const float* __restrict__ pc,
                        const float* __restrict__ keys,
                        const float* __restrict__ values,
                        float* __restrict__ out)
{
#pragma clang fp contract(off)
    __shared__ float4 skA[NPAIR];  // (-2kx_e, -2kx_o, -2ky_e, -2ky_o) 32 KiB
    __shared__ float4 skB[NPAIR];  // (-2kz_e, -2kz_o,  ksq_e,  ksq_o) 32 KiB

    const int tid = threadIdx.x;

    // Stage key pairs: pair j = keys 2j (f0.x,f0.y,f1.x), 2j+1 (f1.y,f2.x,f2.y).
    #pragma unroll
    for (int i = 0; i < NPAIR / BLK; ++i) {
        const int j = tid + i * BLK;
        const float2 f0 = ((const float2*)keys)[3 * j + 0];
        const float2 f1 = ((const float2*)keys)[3 * j + 1];
        const float2 f2 = ((const float2*)keys)[3 * j + 2];
        const float ksq0 = ((f0.x * f0.x) + (f0.y * f0.y)) + (f1.x * f1.x);
        const float ksq1 = ((f1.y * f1.y) + (f2.x * f2.x)) + (f2.y * f2.y);
        skA[j] = make_float4(-2.0f * f0.x, -2.0f * f1.y,
                             -2.0f * f0.y, -2.0f * f2.x);
        skB[j] = make_float4(-2.0f * f1.x, -2.0f * f2.y, ksq0, ksq1);
    }

    // pc passthrough for this block's 64 points: 192 floats = 48 float4.
    {
        const int base = blockIdx.x * (PPB * 3 / 4);  // in float4
        if (tid < PPB * 3 / 4) {
            ((float4*)(out + PC_OFF))[base + tid] =
                ((const float4*)pc)[base + tid];
        }
    }

    const int c = tid & (CC - 1);
    const int g = tid >> 5;                       // point-group 0..15
    const int p0 = blockIdx.x * PPB + g * PP;     // my first point

    // Load my 4 points (12 floats = 3 float4, aligned: 3*p0 % 4 == 0).
    float arr[12];
    {
        const float4* pcv = (const float4*)(pc + 3 * p0);
        #pragma unroll
        for (int i = 0; i < 3; ++i) ((float4*)arr)[i] = pcv[i];
    }
    float PX[PP], PY[PP], PZ[PP], PSQ[PP];
    float bd[PP];
    int bk[PP];
    #pragma unroll
    for (int i = 0; i < PP; ++i) {
        PX[i] = arr[3 * i + 0];
        PY[i] = arr[3 * i + 1];
        PZ[i] = arr[3 * i + 2];
        PSQ[i] = ((PX[i] * PX[i]) + (PY[i] * PY[i])) + (PZ[i] * PZ[i]);
        bd[i] = 3.402823466e38f;
        bk[i] = 0;
    }

    __syncthreads();

    // Main loop: lane c, iter k handles pair j = 32k + c (keys 64k+2c, +1).
    // Per pair per point: 14 scalar rn ops + min3 + cmp + cndmask.
    #pragma unroll 2
    for (int k = 0; k < KIT; ++k) {
        const int j = (k << 5) + c;
        const float4 A  = skA[j];   // (-2kx_e, -2kx_o, -2ky_e, -2ky_o)
        const float4 Bv = skB[j];   // (-2kz_e, -2kz_o,  ksq_e,  ksq_o)
        #pragma unroll
        for (int i = 0; i < PP; ++i) {
            const float t0 = ((PX[i] * A.x) + (PY[i] * A.z)) + (PZ[i] * Bv.x);
            const float d0 = (PSQ[i] + t0) + Bv.z;   // even key
            const float t1 = ((PX[i] * A.y) + (PY[i] * A.w)) + (PZ[i] * Bv.y);
            const float d1 = (PSQ[i] + t1) + Bv.w;   // odd key
            const float nb = min3f(bd[i], d0, d1);
            const bool ch = nb < bd[i];  // strict drop => first-index kept
            bd[i] = nb;
            bk[i] = ch ? k : bk[i];
        }
    }

    // Recover the winning key within pair bk[i] (same scalar expression),
    // then merge the 32 lanes (lexicographic (d2,id) butterfly).
    int bm[PP];
    #pragma unroll
    for (int i = 0; i < PP; ++i) {
        const int j = (bk[i] << 5) + c;
        const float4 A  = skA[j];
        const float4 Bv = skB[j];
        const float ca = ((PX[i] * A.x) + (PY[i] * A.z)) + (PZ[i] * Bv.x);
        const float da = (PSQ[i] + ca) + Bv.z;
        const int m0 = (bk[i] << 6) + (c << 1);
        float d = bd[i];
        int   m = (da == bd[i]) ? m0 : (m0 + 1);  // even preferred on tie
        #pragma unroll
        for (int off = 1; off < CC; off <<= 1) {
            const float od = __shfl_xor(d, off);
            const int   om = __shfl_xor(m, off);
            if (od < d || (od == d && om < m)) { d = od; m = om; }
        }
        bm[i] = m;
    }

    // Epilogue: each point's 32 lanes copy its 64-float value row
    // (1 float2 per lane, coalesced 256B); lane c==0 writes the id.
    #pragma unroll
    for (int i = 0; i < PP; ++i) {
        const float2* vrow = (const float2*)(values + (size_t)bm[i] * DD);
        ((float2*)(out + FEATS_OFF + (size_t)(p0 + i) * DD))[c] = vrow[c];
        if (c == 0) out[IDS_OFF + p0 + i] = (float)bm[i];
    }
}

extern "C" void kernel_launch(void* const* d_in, const int* in_sizes, int n_in,
                              void* d_out, int out_size, void* d_ws, size_t ws_size,
                              hipStream_t stream) {
    const float* pc     = (const float*)d_in[0];
    const float* keys   = (const float*)d_in[1];
    const float* values = (const float*)d_in[2];
    float* out = (float*)d_out;

    dim3 grid(BN / PPB);  // 1024 blocks of 512 threads (2 resident/CU)
    dim3 block(BLK);
    quant_embed_kernel<<<grid, block, 0, stream>>>(pc, keys, values, out);
}

// Round 7
// 110.565 us; speedup vs baseline: 1.0297x; 1.0297x over previous
//
#include <hip/hip_runtime.h>

// CRITICAL: hipcc defaults to -ffp-contract=fast-honor-pragmas, and HIP's
// __fmul_rn/__fadd_rn are PLAIN OPERATORS (not contraction barriers like
// CUDA). This pragma guarantees mul/add are not fused into v_fmac/v_pk_fma,
// so our rounding matches numpy's exactly. (R4 proved this: absmax == 0.0.)
#pragma clang fp contract(off)

typedef float v2f __attribute__((ext_vector_type(2)));

// Forced packed fp32 (VOP3P): per-component rounding == scalar v_mul/v_add.
// NOTE (R10): op_sel on pk_f32 is illegal (aborts).
// NOTE (R14): scalar replacement was SLOWER (64.3 vs 58.1 µs) => pk_f32 is
// NOT half-rate; pk=4cyc. With SIMD-32-corrected busy accounting, both pk
// and scalar variants sit at ~50% VALU occupancy; nothing saturates. The
// limiter is a latency-bound ds_read->compute chain (R15 probes this).
static __device__ __forceinline__ v2f pk_mul(v2f a, v2f b) {
    v2f d;
    asm("v_pk_mul_f32 %0, %1, %2" : "=v"(d) : "v"(a), "v"(b));
    return d;
}
static __device__ __forceinline__ v2f pk_add(v2f a, v2f b) {
    v2f d;
    asm("v_pk_add_f32 %0, %1, %2" : "=v"(d) : "v"(a), "v"(b));
    return d;
}
static __device__ __forceinline__ float min3f(float a, float b, float c) {
    float d;
    asm("v_min3_f32 %0, %1, %2, %3" : "=v"(d) : "v"(a), "v"(b), "v"(c));
    return d;
}

// Problem constants (from reference): B=4, N=16384, M=4096, D=64
#define MM 4096
#define DD 64
#define BN 65536                  // B*N points
#define FEATS_OFF 0               // feats: BN*DD floats
#define IDS_OFF (BN * DD)         // ids:   BN floats (ints stored as float)
#define PC_OFF (IDS_OFF + BN)     // pc:    BN*3 floats passthrough

#define BLK 512                   // threads per block (8 waves)
#define CC 32                     // lanes per point
#define PP 4                      // points per thread (register tile)
#define PPB 64                    // points per block (BLK*PP/CC)
#define NPAIR (MM / 2)            // 2048 key pairs
#define SKN (NPAIR + CC)          // +32 pad pairs so k=63 prefetch is in-bounds
#define KIT (MM / (2 * CC))       // 64 main-loop iterations

// NUMERICS (bit-exact vs numpy fp32 replay — verified R4-R8):
//  - keys stored NEGATED+DOUBLED: rn commutes with sign and 2^k scaling, so
//    cross' = ((px*(-2kx) + py*(-2ky)) + pz*(-2kz)) == -2*cross bit-exact,
//    and d2 = (psq + cross') + ksq == (psq - 2*cross) + ksq == ref bits.
//  - all plain rn (contract off); k_sq/p_sq ascending plain; pk per-lane
//    rounding == scalar. FMA / dropping psq / MFMA are all FORBIDDEN:
//    each changes rounding; a rounding-created tie flips argmin.
//  - argmin: bd via v_min3 (== sequential strict-'<' min, no NaNs); bk =
//    first iter where bd strictly dropped (later equal values don't
//    overwrite => first-index kept); within-pair even preferred on tie at
//    recovery; lexicographic (d2,id) butterfly across lanes.
//
// STRUCTURE (R15, resubmitted R16 — prior run died to container infra,
// kernel never executed): R12/R13/R14 falsified remat, occupancy, and
// pk-rate theories. Corrected-scale counters show NO pipe above ~55% at a
// wall of ~1086 cyc/k-iter/CU vs VALU demand 576 + LDS demand 384 => the
// wall is a latency-bound ds_read->waitcnt->compute chain repeated 64x per
// wave with correlated phases across waves. Fix probed here: explicit
// 1-deep register rotation — prefetch iter k+1's key float4s at the top of
// the body, compute iter k entirely from registers. Pad pairs [2048,2080)
// make the last prefetch in-bounds (loaded, never used in compute).
// Compute sequence is instruction-identical to R12 (best measured, 58.1 µs).
__global__ __launch_bounds__(BLK) __attribute__((amdgpu_waves_per_eu(4, 4)))
void quant_embed_kernel(const float* __restrict__ pc,
                        const float* __restrict__ keys,
                        const float* __restrict__ values,
                        float* __restrict__ out)
{
#pragma clang fp contract(off)
    __shared__ float4 skA[SKN];  // (-2kx_e, -2kx_o, -2ky_e, -2ky_o) 32.5 KiB
    __shared__ float4 skB[SKN];  // (-2kz_e, -2kz_o,  ksq_e,  ksq_o) 32.5 KiB

    const int tid = threadIdx.x;

    // Stage key pairs: pair j = keys 2j (f0.x,f0.y,f1.x), 2j+1 (f1.y,f2.x,f2.y).
    #pragma unroll
    for (int i = 0; i < NPAIR / BLK; ++i) {
        const int j = tid + i * BLK;
        const float2 f0 = ((const float2*)keys)[3 * j + 0];
        const float2 f1 = ((const float2*)keys)[3 * j + 1];
        const float2 f2 = ((const float2*)keys)[3 * j + 2];
        const float ksq0 = ((f0.x * f0.x) + (f0.y * f0.y)) + (f1.x * f1.x);
        const float ksq1 = ((f1.y * f1.y) + (f2.x * f2.x)) + (f2.y * f2.y);
        skA[j] = make_float4(-2.0f * f0.x, -2.0f * f1.y,
                             -2.0f * f0.y, -2.0f * f2.x);
        skB[j] = make_float4(-2.0f * f1.x, -2.0f * f2.y, ksq0, ksq1);
    }
    // Pad pairs (read by the final prefetch, never used in compute).
    if (tid < CC) {
        skA[NPAIR + tid] = make_float4(0.f, 0.f, 0.f, 0.f);
        skB[NPAIR + tid] = make_float4(0.f, 0.f, 0.f, 0.f);
    }

    // pc passthrough for this block's 64 points: 192 floats = 48 float4.
    {
        const int base = blockIdx.x * (PPB * 3 / 4);  // in float4
        if (tid < PPB * 3 / 4) {
            ((float4*)(out + PC_OFF))[base + tid] =
                ((const float4*)pc)[base + tid];
        }
    }

    const int c = tid & (CC - 1);
    const int g = tid >> 5;                       // point-group 0..15
    const int p0 = blockIdx.x * PPB + g * PP;     // my first point

    // Load my 4 points (12 floats = 3 float4, aligned: 3*p0 % 4 == 0).
    float arr[12];
    {
        const float4* pcv = (const float4*)(pc + 3 * p0);
        #pragma unroll
        for (int i = 0; i < 3; ++i) ((float4*)arr)[i] = pcv[i];
    }
    v2f PX[PP], PY[PP], PZ[PP], PSQ[PP];
    float bd[PP];
    int bk[PP];
    #pragma unroll
    for (int i = 0; i < PP; ++i) {
        const float px = arr[3 * i + 0];
        const float py = arr[3 * i + 1];
        const float pz = arr[3 * i + 2];
        const float psq = ((px * px) + (py * py)) + (pz * pz);
        PX[i] = (v2f){px, px};
        PY[i] = (v2f){py, py};
        PZ[i] = (v2f){pz, pz};
        PSQ[i] = (v2f){psq, psq};
        bd[i] = 3.402823466e38f;
        bk[i] = 0;
    }

    __syncthreads();

    // Main loop: lane c, iter k handles pair j = 32k + c (keys 64k+2c, +1).
    // Register-rotated prefetch: iter k computes from registers while iter
    // k+1's key data is in flight. 10 issue slots per key-pair per point.
    float4 A  = skA[c];
    float4 Bv = skB[c];
    #pragma unroll 4
    for (int k = 0; k < KIT; ++k) {
        const int jn = ((k + 1) << 5) + c;
        const float4 An = skA[jn];
        const float4 Bn = skB[jn];
        const v2f Kx = {A.x,  A.y};
        const v2f Ky = {A.z,  A.w};
        const v2f Kz = {Bv.x, Bv.y};
        const v2f Ks = {Bv.z, Bv.w};
        #pragma unroll
        for (int i = 0; i < PP; ++i) {
            v2f t = pk_add(pk_mul(Kx, PX[i]), pk_mul(Ky, PY[i]));
            t = pk_add(t, pk_mul(Kz, PZ[i]));
            t = pk_add(PSQ[i], t);       // psq - 2*cross (keys negated)
            t = pk_add(t, Ks);           // + ksq
            const float nb = min3f(bd[i], t.x, t.y);
            const bool ch = nb < bd[i];  // strict drop => first-index kept
            bd[i] = nb;
            bk[i] = ch ? k : bk[i];
        }
        A = An;
        Bv = Bn;
    }

    // Recover the winning key within pair bk[i] (scalar plain == pk bits),
    // then merge the 32 lanes (lexicographic (d2,id) butterfly).
    int bm[PP];
    #pragma unroll
    for (int i = 0; i < PP; ++i) {
        const int j = (bk[i] << 5) + c;
        const float4 Ar  = skA[j];
        const float4 Br = skB[j];
        const float ca = ((PX[i].x * Ar.x) + (PY[i].x * Ar.z)) + (PZ[i].x * Br.x);
        const float da = (PSQ[i].x + ca) + Br.z;
        const int m0 = (bk[i] << 6) + (c << 1);
        float d = bd[i];
        int   m = (da == bd[i]) ? m0 : (m0 + 1);  // even preferred on tie
        #pragma unroll
        for (int off = 1; off < CC; off <<= 1) {
            const float od = __shfl_xor(d, off);
            const int   om = __shfl_xor(m, off);
            if (od < d || (od == d && om < m)) { d = od; m = om; }
        }
        bm[i] = m;
    }

    // Epilogue: each point's 32 lanes copy its 64-float value row
    // (1 float2 per lane, coalesced 256B); lane c==0 writes the id.
    #pragma unroll
    for (int i = 0; i < PP; ++i) {
        const float2* vrow = (const float2*)(values + (size_t)bm[i] * DD);
        ((float2*)(out + FEATS_OFF + (size_t)(p0 + i) * DD))[c] = vrow[c];
        if (c == 0) out[IDS_OFF + p0 + i] = (float)bm[i];
    }
}

extern "C" void kernel_launch(void* const* d_in, const int* in_sizes, int n_in,
                              void* d_out, int out_size, void* d_ws, size_t ws_size,
                              hipStream_t stream) {
    const float* pc     = (const float*)d_in[0];
    const float* keys   = (const float*)d_in[1];
    const float* values = (const float*)d_in[2];
    float* out = (float*)d_out;

    dim3 grid(BN / PPB);  // 1024 blocks of 512 threads (2 resident/CU)
    dim3 block(BLK);
    quant_embed_kernel<<<grid, block, 0, stream>>>(pc, keys, values, out);
}

// Round 8
// 108.996 us; speedup vs baseline: 1.0445x; 1.0144x over previous
//
#include <hip/hip_runtime.h>

// CRITICAL: hipcc defaults to -ffp-contract=fast-honor-pragmas, and HIP's
// __fmul_rn/__fadd_rn are PLAIN OPERATORS (not contraction barriers like
// CUDA). This pragma guarantees mul/add are not fused into v_fmac/v_pk_fma,
// so our rounding matches numpy's exactly. (R4 proved this: absmax == 0.0.)
#pragma clang fp contract(off)

// HISTORY:
//  R10: op_sel on pk_f32 is illegal (aborts).
//  R12: PP=8->4 freed regs, flat => remat theory dead.
//  R13: occupancy 2.4->3.9 waves/SIMD, flat => latency-hiding theory dead.
//  R14: "scalar" C code was 10% slower — BUT the SLP vectorizer very likely
//       re-packed the isomorphic even/odd chains into v_pk ops, so R14
//       discriminated nothing.
//  R15: 1-deep register prefetch rotation, flat => exposed-LDS-latency dead.
//  The wall is pinned at ~272 cyc/SIMD/wave-iter across ALL rounds. The one
//  model fitting everything: v_pk_*_f32 = 8 cyc/wave64 instr (HALF the
//  per-component rate of scalar fp32): 7pk*8 + 6 = 248+overhead ≈ 272,
//  i.e. VALU ~91% saturated => occupancy/prefetch/scheduling all no-ops.
//  R16 pins scalar v_mul/v_add via INLINE ASM (SLP cannot vectorize asm):
//  VALU demand 136 cyc/pt-group-iter. If pk=8cyc: ~58 -> ~35-42 µs.
static __device__ __forceinline__ float smul(float a, float b) {
    float d;
    asm("v_mul_f32 %0, %1, %2" : "=v"(d) : "v"(a), "v"(b));
    return d;
}
static __device__ __forceinline__ float sadd(float a, float b) {
    float d;
    asm("v_add_f32 %0, %1, %2" : "=v"(d) : "v"(a), "v"(b));
    return d;
}
static __device__ __forceinline__ float min3f(float a, float b, float c) {
    float d;
    asm("v_min3_f32 %0, %1, %2, %3" : "=v"(d) : "v"(a), "v"(b), "v"(c));
    return d;
}

// Problem constants (from reference): B=4, N=16384, M=4096, D=64
#define MM 4096
#define DD 64
#define BN 65536                  // B*N points
#define FEATS_OFF 0               // feats: BN*DD floats
#define IDS_OFF (BN * DD)         // ids:   BN floats (ints stored as float)
#define PC_OFF (IDS_OFF + BN)     // pc:    BN*3 floats passthrough

#define BLK 512                   // threads per block (8 waves)
#define CC 32                     // lanes per point
#define PP 4                      // points per thread (register tile)
#define PPB 64                    // points per block (BLK*PP/CC)
#define NPAIR (MM / 2)            // 2048 key pairs
#define KIT (MM / (2 * CC))       // 64 main-loop iterations

// NUMERICS (bit-exact vs numpy fp32 replay — verified R4-R8, R14):
//  - keys stored NEGATED+DOUBLED: rn commutes with sign and 2^k scaling, so
//    cross' = ((px*(-2kx) + py*(-2ky)) + pz*(-2kz)) == -2*cross bit-exact,
//    and d2 = (psq + cross') + ksq == (psq - 2*cross) + ksq == ref bits.
//  - all plain rn (contract off); asm v_mul/v_add are rn; association order
//    identical to the verified R14 scalar expression (absmax 0.0). FMA /
//    dropping psq / MFMA are FORBIDDEN: each changes rounding; a
//    rounding-created tie flips argmin's first-index rule.
//  - argmin: bd via v_min3 (== sequential strict-'<' min, no NaNs); bk =
//    first iter where bd strictly dropped (later equal values don't
//    overwrite => first-index kept); within-pair even preferred on tie at
//    recovery; lexicographic (d2,id) butterfly across lanes.
__global__ __launch_bounds__(BLK) __attribute__((amdgpu_waves_per_eu(4, 4)))
void quant_embed_kernel(const float* __restrict__ pc,
                        const float* __restrict__ keys,
                        const float* __restrict__ values,
                        float* __restrict__ out)
{
#pragma clang fp contract(off)
    __shared__ float4 skA[NPAIR];  // (-2kx_e, -2kx_o, -2ky_e, -2ky_o) 32 KiB
    __shared__ float4 skB[NPAIR];  // (-2kz_e, -2kz_o,  ksq_e,  ksq_o) 32 KiB

    const int tid = threadIdx.x;

    // Stage key pairs: pair j = keys 2j (f0.x,f0.y,f1.x), 2j+1 (f1.y,f2.x,f2.y).
    #pragma unroll
    for (int i = 0; i < NPAIR / BLK; ++i) {
        const int j = tid + i * BLK;
        const float2 f0 = ((const float2*)keys)[3 * j + 0];
        const float2 f1 = ((const float2*)keys)[3 * j + 1];
        const float2 f2 = ((const float2*)keys)[3 * j + 2];
        const float ksq0 = ((f0.x * f0.x) + (f0.y * f0.y)) + (f1.x * f1.x);
        const float ksq1 = ((f1.y * f1.y) + (f2.x * f2.x)) + (f2.y * f2.y);
        skA[j] = make_float4(-2.0f * f0.x, -2.0f * f1.y,
                             -2.0f * f0.y, -2.0f * f2.x);
        skB[j] = make_float4(-2.0f * f1.x, -2.0f * f2.y, ksq0, ksq1);
    }

    // pc passthrough for this block's 64 points: 192 floats = 48 float4.
    {
        const int base = blockIdx.x * (PPB * 3 / 4);  // in float4
        if (tid < PPB * 3 / 4) {
            ((float4*)(out + PC_OFF))[base + tid] =
                ((const float4*)pc)[base + tid];
        }
    }

    const int c = tid & (CC - 1);
    const int g = tid >> 5;                       // point-group 0..15
    const int p0 = blockIdx.x * PPB + g * PP;     // my first point

    // Load my 4 points (12 floats = 3 float4, aligned: 3*p0 % 4 == 0).
    float arr[12];
    {
        const float4* pcv = (const float4*)(pc + 3 * p0);
        #pragma unroll
        for (int i = 0; i < 3; ++i) ((float4*)arr)[i] = pcv[i];
    }
    float PX[PP], PY[PP], PZ[PP], PSQ[PP];
    float bd[PP];
    int bk[PP];
    #pragma unroll
    for (int i = 0; i < PP; ++i) {
        PX[i] = arr[3 * i + 0];
        PY[i] = arr[3 * i + 1];
        PZ[i] = arr[3 * i + 2];
        PSQ[i] = ((PX[i] * PX[i]) + (PY[i] * PY[i])) + (PZ[i] * PZ[i]);
        bd[i] = 3.402823466e38f;
        bk[i] = 0;
    }

    __syncthreads();

    // Main loop: lane c, iter k handles pair j = 32k + c (keys 64k+2c, +1).
    // Per pair per point: 14 asm-pinned scalar rn ops + min3 + cmp + cndmask.
    #pragma unroll 2
    for (int k = 0; k < KIT; ++k) {
        const int j = (k << 5) + c;
        const float4 A  = skA[j];   // (-2kx_e, -2kx_o, -2ky_e, -2ky_o)
        const float4 Bv = skB[j];   // (-2kz_e, -2kz_o,  ksq_e,  ksq_o)
        #pragma unroll
        for (int i = 0; i < PP; ++i) {
            // even key: ((px*kx + py*ky) + pz*kz); (psq + t) + ksq
            const float e0 = smul(PX[i], A.x);
            const float e1 = smul(PY[i], A.z);
            const float e2 = sadd(e0, e1);
            const float e3 = smul(PZ[i], Bv.x);
            const float e4 = sadd(e2, e3);
            const float e5 = sadd(PSQ[i], e4);
            const float d0 = sadd(e5, Bv.z);
            // odd key
            const float o0 = smul(PX[i], A.y);
            const float o1 = smul(PY[i], A.w);
            const float o2 = sadd(o0, o1);
            const float o3 = smul(PZ[i], Bv.y);
            const float o4 = sadd(o2, o3);
            const float o5 = sadd(PSQ[i], o4);
            const float d1 = sadd(o5, Bv.w);
            const float nb = min3f(bd[i], d0, d1);
            const bool ch = nb < bd[i];  // strict drop => first-index kept
            bd[i] = nb;
            bk[i] = ch ? k : bk[i];
        }
    }

    // Recover the winning key within pair bk[i] (same rn scalar expression),
    // then merge the 32 lanes (lexicographic (d2,id) butterfly).
    int bm[PP];
    #pragma unroll
    for (int i = 0; i < PP; ++i) {
        const int j = (bk[i] << 5) + c;
        const float4 A  = skA[j];
        const float4 Bv = skB[j];
        const float ca = ((PX[i] * A.x) + (PY[i] * A.z)) + (PZ[i] * Bv.x);
        const float da = (PSQ[i] + ca) + Bv.z;
        const int m0 = (bk[i] << 6) + (c << 1);
        float d = bd[i];
        int   m = (da == bd[i]) ? m0 : (m0 + 1);  // even preferred on tie
        #pragma unroll
        for (int off = 1; off < CC; off <<= 1) {
            const float od = __shfl_xor(d, off);
            const int   om = __shfl_xor(m, off);
            if (od < d || (od == d && om < m)) { d = od; m = om; }
        }
        bm[i] = m;
    }

    // Epilogue: each point's 32 lanes copy its 64-float value row
    // (1 float2 per lane, coalesced 256B); lane c==0 writes the id.
    #pragma unroll
    for (int i = 0; i < PP; ++i) {
        const float2* vrow = (const float2*)(values + (size_t)bm[i] * DD);
        ((float2*)(out + FEATS_OFF + (size_t)(p0 + i) * DD))[c] = vrow[c];
        if (c == 0) out[IDS_OFF + p0 + i] = (float)bm[i];
    }
}

extern "C" void kernel_launch(void* const* d_in, const int* in_sizes, int n_in,
                              void* d_out, int out_size, void* d_ws, size_t ws_size,
                              hipStream_t stream) {
    const float* pc     = (const float*)d_in[0];
    const float* keys   = (const float*)d_in[1];
    const float* values = (const float*)d_in[2];
    float* out = (float*)d_out;

    dim3 grid(BN / PPB);  // 1024 blocks of 512 threads (2 resident/CU)
    dim3 block(BLK);
    quant_embed_kernel<<<grid, block, 0, stream>>>(pc, keys, values, out);
}